// Round 4
// baseline (630.013 us; speedup 1.0000x reference)
//
#include <hip/hip_runtime.h>
#include <stdint.h>

// ---------- types ----------
typedef __attribute__((ext_vector_type(8))) __bf16 bf16x8;
typedef __attribute__((ext_vector_type(4))) float floatx4;

#define DEV __device__ __forceinline__

DEV unsigned short f2bf(float f) {
    union { float f; unsigned u; } uf; uf.f = f;
    unsigned u = uf.u;
    unsigned r = (u + 0x7fffu + ((u >> 16) & 1u)) >> 16;  // RNE
    return (unsigned short)r;
}

DEV float fast_exp2(float x) {
#if __has_builtin(__builtin_amdgcn_exp2f)
    return __builtin_amdgcn_exp2f(x);
#else
    return exp2f(x);
#endif
}

DEV unsigned pack_trunc2(float lo, float hi) {
    // (trunc_bf16(hi) << 16) | trunc_bf16(lo) in one v_perm_b32
    return __builtin_amdgcn_perm(__float_as_uint(hi), __float_as_uint(lo), 0x07060302u);
}

DEV void async16(const void* g, void* l) {
    __builtin_amdgcn_global_load_lds(
        (const __attribute__((address_space(1))) void*)g,
        (__attribute__((address_space(3))) void*)l, 16, 0, 0);
}

// ---------- merged cast: x (8M f32), 4 weights (4M f32), 3 biases ----------
__global__ void cast_all_kernel(const float* __restrict__ x,
                                const float* __restrict__ Wq, const float* __restrict__ Wk,
                                const float* __restrict__ Wv, const float* __restrict__ Wo,
                                const float* __restrict__ bq, const float* __restrict__ bk,
                                const float* __restrict__ bv,
                                unsigned short* __restrict__ xb,
                                unsigned short* __restrict__ wqkv,
                                unsigned short* __restrict__ wo,
                                float* __restrict__ bqkv) {
    const int NX = 2097152;   // float4s in x
    const int NW = 262144;    // float4s per weight
    int i = blockIdx.x * blockDim.x + threadIdx.x;
    if (i < NX) {
        float4 v = reinterpret_cast<const float4*>(x)[i];
        ushort4 o;
        o.x = f2bf(v.x); o.y = f2bf(v.y); o.z = f2bf(v.z); o.w = f2bf(v.w);
        reinterpret_cast<ushort4*>(xb)[i] = o;
        return;
    }
    int j = i - NX;
    if (j < 4 * NW) {
        int seg = j >> 18, off = j & (NW - 1);
        const float* src = (seg == 0) ? Wq : (seg == 1) ? Wk : (seg == 2) ? Wv : Wo;
        unsigned short* dst = (seg < 3) ? (wqkv + seg * 1048576) : wo;
        float4 v = reinterpret_cast<const float4*>(src)[off];
        ushort4 o;
        o.x = f2bf(v.x); o.y = f2bf(v.y); o.z = f2bf(v.z); o.w = f2bf(v.w);
        reinterpret_cast<ushort4*>(dst)[off] = o;
        return;
    }
    int k = j - 4 * NW;
    if (k < 768) {  // 3 x 1024 floats of bias as float4
        int seg = k >> 8, off = k & 255;
        const float* src = (seg == 0) ? bq : (seg == 1) ? bk : bv;
        reinterpret_cast<float4*>(bqkv)[k] = reinterpret_cast<const float4*>(src)[off];
    }
}

// ---------- 128x128 GEMM, C = A(MxK) * B(NxK)^T, bf16 in, fp32 acc ----------
// Grid: x = bm, y = bn (8 consecutive blocks -> 8 XCDs share one B-tile).
// MODE 0: QKV epilogue. bn<8: Q (scaled by Dh^-0.5*log2e), 8..15: K, 16..23: V
//         V^T gets virtual-key perm v=(a&15)*4+(a>>4) per 64-key block
//         (round-0 verified pairing with the LDS-P read path in attn).
// MODE 1: out-proj epilogue (bias add, fp32 store via LDS transpose)
template <int MODE>
__global__ __launch_bounds__(256)
void gemm128(const unsigned short* __restrict__ A,   // M x K  (K-contig)
             const unsigned short* __restrict__ B,   // N x K  (K-contig)
             const float* __restrict__ bias,         // N
             unsigned short* __restrict__ q_ws,
             unsigned short* __restrict__ k_ws,
             unsigned short* __restrict__ v_ws,
             float* __restrict__ fout) {
    constexpr int K = 1024;
    __shared__ alignas(16) unsigned short smem[128 * 136];  // sA+sB / sT union
    unsigned short* sA = smem;             // 128*64
    unsigned short* sB = smem + 128 * 64;  // 128*64
    unsigned short* sT = smem;             // 128*136 (transpose staging, bf16)
    float* sT32 = reinterpret_cast<float*>(smem);  // 64*132 (fp32 staging)

    const int tid = threadIdx.x;
    const int w = tid >> 6, lane = tid & 63, quad = lane >> 4, l16 = lane & 15;
    const int wr = w >> 1, wc = w & 1;
    const int bm = blockIdx.x, bn = blockIdx.y;
    const int arow0 = bm * 128, brow0 = bn * 128;

    floatx4 acc[4][4];
#pragma unroll
    for (int i = 0; i < 4; i++)
#pragma unroll
        for (int j = 0; j < 4; j++) acc[i][j] = (floatx4){0.f, 0.f, 0.f, 0.f};

    for (int k0 = 0; k0 < K; k0 += 64) {
#pragma unroll
        for (int i = 0; i < 4; i++) {
            int cb = i * 256 + w * 64;
            int ci = cb + lane;
            int row = ci >> 3, cl = ci & 7, cs = cl ^ (row & 7);
            async16(A + (size_t)(arow0 + row) * K + k0 + cs * 8, (char*)sA + cb * 16);
            async16(B + (size_t)(brow0 + row) * K + k0 + cs * 8, (char*)sB + cb * 16);
        }
        __syncthreads();
#pragma unroll
        for (int kk = 0; kk < 2; kk++) {
            bf16x8 aF[4], bF[4];
#pragma unroll
            for (int i = 0; i < 4; i++) {
                int row = wr * 64 + i * 16 + l16;
                int c = kk * 4 + quad, ph = c ^ (row & 7);
                aF[i] = *reinterpret_cast<const bf16x8*>(sA + row * 64 + ph * 8);
            }
#pragma unroll
            for (int j = 0; j < 4; j++) {
                int row = wc * 64 + j * 16 + l16;
                int c = kk * 4 + quad, ph = c ^ (row & 7);
                bF[j] = *reinterpret_cast<const bf16x8*>(sB + row * 64 + ph * 8);
            }
#pragma unroll
            for (int i = 0; i < 4; i++)
#pragma unroll
                for (int j = 0; j < 4; j++)
                    acc[i][j] = __builtin_amdgcn_mfma_f32_16x16x32_bf16(
                        aF[i], bF[j], acc[i][j], 0, 0, 0);
        }
        __syncthreads();
    }

    if (MODE == 1) {
        // fp32 out via LDS transpose, two 64-row chunks
#pragma unroll
        for (int ch = 0; ch < 2; ch++) {
            if (ch) __syncthreads();
            if (wr == ch) {
#pragma unroll
                for (int j = 0; j < 4; j++) {
                    const int c = wc * 64 + j * 16 + l16;
                    const float bia = bias[brow0 + c];
#pragma unroll
                    for (int i = 0; i < 4; i++) {
                        int s_loc = i * 16 + quad * 4;
#pragma unroll
                        for (int r = 0; r < 4; r++)
                            sT32[(s_loc + r) * 132 + c] = acc[i][j][r] + bia;
                    }
                }
            }
            __syncthreads();
            const int cpos = (tid & 31) * 4;
#pragma unroll
            for (int it = 0; it < 8; it++) {
                int s_loc = (tid >> 5) + it * 8;
                int grow = arow0 + ch * 64 + s_loc;
                float4 vv = *reinterpret_cast<const float4*>(sT32 + s_loc * 132 + cpos);
                *reinterpret_cast<float4*>(fout + (size_t)grow * 1024 + brow0 + cpos) = vv;
            }
        }
    } else if (bn < 16) {
        // Q or K via LDS transpose -> coalesced 16B stores into (bh, s, d)
        unsigned short* dst = (bn < 8) ? q_ws : k_ws;
        const float sc = (bn < 8) ? 0.18033688f : 1.0f;  // Dh^-0.5 * log2(e) for Q
#pragma unroll
        for (int j = 0; j < 4; j++) {
            const int c = wc * 64 + j * 16 + l16;
            const float bia = bias[brow0 + c];
#pragma unroll
            for (int i = 0; i < 4; i++) {
                int s_loc = wr * 64 + i * 16 + quad * 4;
#pragma unroll
                for (int r = 0; r < 4; r++)
                    sT[(s_loc + r) * 136 + c] = f2bf((acc[i][j][r] + bia) * sc);
            }
        }
        __syncthreads();
        const int nnbase = (bn & 7) * 128;
        const int c0 = (tid & 15) * 8;
        const int h = (nnbase + c0) >> 6, d = c0 & 63;
#pragma unroll
        for (int it = 0; it < 8; it++) {
            int s_loc = (tid >> 4) + it * 16;
            int s = arow0 + s_loc;
            int bb = s >> 11, s4 = s & 2047;
            uint4 vdat = *reinterpret_cast<const uint4*>(sT + s_loc * 136 + c0);
            *reinterpret_cast<uint4*>(
                dst + ((size_t)(bb * 16 + h) * 2048 + s4) * 64 + d) = vdat;
        }
    } else {
        // V: transpose via LDS, store (bh, d, s_virtual) coalesced.
        // ROUND-0 VERIFIED 64-key virtual perm: s_local = wr*64 + a,
        // a = i*16+quad*4+r,  v = (a&15)*4 + (a>>4) = (quad*4+r)*4 + i
#pragma unroll
        for (int j = 0; j < 4; j++) {
            const int c = wc * 64 + j * 16 + l16;  // block-local col 0..127
            const float bia = bias[brow0 + c];
#pragma unroll
            for (int i = 0; i < 4; i++) {
#pragma unroll
                for (int r = 0; r < 4; r++) {
                    int v = wr * 64 + (quad * 4 + r) * 4 + i;
                    sT[c * 136 + v] = f2bf(acc[i][j][r] + bia);
                }
            }
        }
        __syncthreads();
        const int bb = bm >> 4, blk = bm & 15;
        const int chunk = tid & 15;
#pragma unroll
        for (int it = 0; it < 8; it++) {
            int row = (tid >> 4) + it * 16;   // block-local col = h*64+d part
            int h = (bn - 16) * 2 + (row >> 6), d = row & 63;
            ushort4 lo = *reinterpret_cast<const ushort4*>(sT + row * 136 + chunk * 8);
            ushort4 hi = *reinterpret_cast<const ushort4*>(sT + row * 136 + chunk * 8 + 4);
            size_t off = ((size_t)(bb * 16 + h) * 64 + d) * 2048 + blk * 128 + chunk * 8;
            *reinterpret_cast<ushort4*>(v_ws + off) = lo;
            *reinterpret_cast<ushort4*>(v_ws + off + 4) = hi;
        }
    }
}

// ---------- flash attention: one block = (bh, 64 q rows) ----------
// 64-key tiles. K double-buffered in LDS (async16, one barrier per tile).
// V is NOT staged: v_ws (bh, d, s_virtual) makes each PV B-fragment a
// single contiguous 16B global load (L2-resident: all 32 q-blocks of a bh
// share one XCD). V loads are issued at tile start -> full QK+exp phase
// covers L2 latency; vmcnt-tracked, no barrier involvement.
// SWAPPED QK^T (round-3 verified): sAcc = mfma(K,Q); lane (quad,l16) owns
// q-row l16, keys 16j+4quad+r. P round-trips through per-wave sP (layout:
// position p holds key (p&3)*16+(p>>2), chunk-XOR swizzled).
// LDS 24 KB -> 6 blocks/CU; launch_bounds(256,6) caps VGPR for 6 waves/SIMD.
__global__ __launch_bounds__(256, 6)
void attn_kernel(const unsigned short* __restrict__ q_ws,
                 const unsigned short* __restrict__ k_ws,
                 const unsigned short* __restrict__ v_ws,
                 unsigned short* __restrict__ o_ws) {
    __shared__ alignas(16) unsigned short smem[12288];  // 24 KB
    // [0,4096): sK buf0   [4096,8192): sK buf1
    // [8192,12288): sP, wave w at +w*1024 (16 q-rows x 64 vkeys, chunk-XOR)

    const int tid = threadIdx.x;
    const int w = tid >> 6, lane = tid & 63, quad = lane >> 4, l16 = lane & 15;
    // XCD-affinity remap: all 32 q-blocks of one bh land on one XCD (id%8)
    const int id = blockIdx.x;
    const int bh = (id >> 8) * 8 + (id & 7);
    const int q0 = ((id >> 3) & 31) * 64;
    const size_t base = (size_t)bh * 2048 * 64;

    unsigned short* sPw = smem + 8192 + w * 1024;

    bf16x8 aQ[2];
    {
        int qrow = q0 + w * 16 + l16;
        const unsigned short* qp = q_ws + base + (size_t)qrow * 64 + quad * 8;
        aQ[0] = *reinterpret_cast<const bf16x8*>(qp);
        aQ[1] = *reinterpret_cast<const bf16x8*>(qp + 32);
    }

    // K staging: 64x64 tile = 512 chunks of 16B; 2 chunks per thread
    const unsigned short* kg[2];
    int loff[2];
#pragma unroll
    for (int it = 0; it < 2; it++) {
        int ci = it * 256 + tid;
        int row = ci >> 3, cl = ci & 7, cs = cl ^ (row & 7);
        kg[it] = k_ws + base + (size_t)row * 64 + cs * 8;
        loff[it] = ci * 8;  // shorts
    }
    // V direct-load base: per-(jd,ks) fragment = 16B at (d=jd*16+l16,
    // pos=t*64 + ks*32 + quad*8)
    const unsigned short* vbase = v_ws + base + (size_t)l16 * 2048 + quad * 8;

    const __bf16 one = (__bf16)1.0f;
    const bf16x8 vOnes = {one, one, one, one, one, one, one, one};

    floatx4 oAcc[4], rsAcc;
#pragma unroll
    for (int j = 0; j < 4; j++) oAcc[j] = (floatx4){0.f, 0.f, 0.f, 0.f};
    rsAcc = (floatx4){0.f, 0.f, 0.f, 0.f};

    // prologue: stage K tile 0 into buf 0
    {
#pragma unroll
        for (int it = 0; it < 2; it++) async16(kg[it], smem + loff[it]);
    }

    for (int t = 0; t < 32; t++) {
        const int b = t & 1;
        const unsigned short* sK = smem + b * 4096;
        __syncthreads();  // K tile t staged (vmcnt drain); buf b^1 free

        if (t < 31) {
            const int kv0 = (t + 1) * 64;
            unsigned short* dK = smem + (b ^ 1) * 4096;
#pragma unroll
            for (int it = 0; it < 2; it++)
                async16(kg[it] + (size_t)kv0 * 64, dK + loff[it]);
        }

        // V loads issued at tile start — covered by the QK+exp phase
        bf16x8 bV[4][2];
#pragma unroll
        for (int jd = 0; jd < 4; jd++)
#pragma unroll
            for (int ks = 0; ks < 2; ks++)
                bV[jd][ks] = *reinterpret_cast<const bf16x8*>(
                    vbase + (size_t)(jd * 16) * 2048 + t * 64 + ks * 32);

        // S'^T = K Q'^T over 64 keys (log2e, 1/sqrt(Dh) pre-folded into Q).
        // sAcc[j][r] at lane (quad,l16): key = 16j + 4quad + r, q = l16.
        floatx4 sAcc[4];
#pragma unroll
        for (int j = 0; j < 4; j++) sAcc[j] = (floatx4){0.f, 0.f, 0.f, 0.f};
#pragma unroll
        for (int kk = 0; kk < 2; kk++) {
#pragma unroll
            for (int j = 0; j < 4; j++) {
                int krow = j * 16 + l16;
                int ph = (kk * 4 + quad) ^ (krow & 7);
                bf16x8 aK = *reinterpret_cast<const bf16x8*>(sK + krow * 64 + ph * 8);
                sAcc[j] = __builtin_amdgcn_mfma_f32_16x16x32_bf16(aK, aQ[kk], sAcc[j], 0, 0, 0);
            }
        }

        // p = exp2(s'^T); lane owns q-row l16, writes positions
        // p = 16*quad + 4*r + j (two contiguous 16B chunks, chunk-XOR layout)
        {
            float e00 = fast_exp2(sAcc[0][0]), e10 = fast_exp2(sAcc[1][0]);
            float e20 = fast_exp2(sAcc[2][0]), e30 = fast_exp2(sAcc[3][0]);
            float e01 = fast_exp2(sAcc[0][1]), e11 = fast_exp2(sAcc[1][1]);
            float e21 = fast_exp2(sAcc[2][1]), e31 = fast_exp2(sAcc[3][1]);
            float e02 = fast_exp2(sAcc[0][2]), e12 = fast_exp2(sAcc[1][2]);
            float e22 = fast_exp2(sAcc[2][2]), e32 = fast_exp2(sAcc[3][2]);
            float e03 = fast_exp2(sAcc[0][3]), e13 = fast_exp2(sAcc[1][3]);
            float e23 = fast_exp2(sAcc[2][3]), e33 = fast_exp2(sAcc[3][3]);
            uint4 w0, w1;
            w0.x = pack_trunc2(e00, e10);
            w0.y = pack_trunc2(e20, e30);
            w0.z = pack_trunc2(e01, e11);
            w0.w = pack_trunc2(e21, e31);
            w1.x = pack_trunc2(e02, e12);
            w1.y = pack_trunc2(e22, e32);
            w1.z = pack_trunc2(e03, e13);
            w1.w = pack_trunc2(e23, e33);
            const int xr = l16 & 7;
            *reinterpret_cast<uint4*>(sPw + l16 * 64 + (((2 * quad) ^ xr) << 3)) = w0;
            *reinterpret_cast<uint4*>(sPw + l16 * 64 + (((2 * quad + 1) ^ xr) << 3)) = w1;
        }
        asm volatile("s_waitcnt lgkmcnt(0)" ::: "memory");
        __builtin_amdgcn_sched_barrier(0);

        // O += P V ; rowsum += P * ones  (round-0 verified read path)
        bf16x8 aP[2];
#pragma unroll
        for (int ks = 0; ks < 2; ks++)
            aP[ks] = *reinterpret_cast<const bf16x8*>(
                sPw + l16 * 64 + (((ks * 4 + quad) ^ (l16 & 7)) << 3));
#pragma unroll
        for (int jd = 0; jd < 4; jd++) {
#pragma unroll
            for (int ks = 0; ks < 2; ks++)
                oAcc[jd] = __builtin_amdgcn_mfma_f32_16x16x32_bf16(
                    aP[ks], bV[jd][ks], oAcc[jd], 0, 0, 0);
        }
#pragma unroll
        for (int ks = 0; ks < 2; ks++)
            rsAcc = __builtin_amdgcn_mfma_f32_16x16x32_bf16(aP[ks], vOnes, rsAcc, 0, 0, 0);
    }

    // epilogue: rsAcc[r] = row sum for q=quad*4+r (replicated across l16)
    float inv[4];
#pragma unroll
    for (int r = 0; r < 4; r++) inv[r] = 1.0f / rsAcc[r];
    const int bb = bh >> 4, h = bh & 15;
#pragma unroll
    for (int jd = 0; jd < 4; jd++) {
        int d = jd * 16 + l16;
#pragma unroll
        for (int r = 0; r < 4; r++) {
            int s = q0 + w * 16 + quad * 4 + r;
            float v = oAcc[jd][r] * inv[r];
            o_ws[((size_t)bb * 2048 + s) * 1024 + h * 64 + d] = f2bf(v);
        }
    }
}

// ---------- launch ----------
extern "C" void kernel_launch(void* const* d_in, const int* in_sizes, int n_in,
                              void* d_out, int out_size, void* d_ws, size_t ws_size,
                              hipStream_t stream) {
    const float* x  = (const float*)d_in[0];
    const float* Wq = (const float*)d_in[1];
    const float* bq = (const float*)d_in[2];
    const float* Wk = (const float*)d_in[3];
    const float* bk = (const float*)d_in[4];
    const float* Wv = (const float*)d_in[5];
    const float* bv = (const float*)d_in[6];
    const float* Wo = (const float*)d_in[7];
    const float* bo = (const float*)d_in[8];
    float* out = (float*)d_out;

    char* ws = (char*)d_ws;
    unsigned short* xb   = (unsigned short*)(ws);                       // 16 MB
    unsigned short* wqkv = (unsigned short*)(ws + (16ull << 20));       // 6 MB
    unsigned short* wo   = (unsigned short*)(ws + (22ull << 20));       // 2 MB
    float*          bqkv = (float*)(ws + (24ull << 20));                // 12 KB
    unsigned short* q_ws = (unsigned short*)(ws + (25ull << 20));       // 16 MB
    unsigned short* k_ws = (unsigned short*)(ws + (41ull << 20));       // 16 MB
    unsigned short* v_ws = (unsigned short*)(ws + (57ull << 20));       // 16 MB
    unsigned short* o_ws = xb;  // alias: x_bf dead after QKV GEMM

    // one cast kernel: 2097152 (x) + 1048576 (W) + 768 (bias) float4 slots
    cast_all_kernel<<<12291, 256, 0, stream>>>(x, Wq, Wk, Wv, Wo, bq, bk, bv,
                                               xb, wqkv, wo, bqkv);

    gemm128<0><<<dim3(64, 24), 256, 0, stream>>>(xb, wqkv, bqkv, q_ws, k_ws, v_ws, nullptr);
    attn_kernel<<<2048, 256, 0, stream>>>(q_ws, k_ws, v_ws, o_ws);
    gemm128<1><<<dim3(64, 8), 256, 0, stream>>>(o_ws, wo, bo, nullptr, nullptr, nullptr, out);
}

// Round 5
// 275.881 us; speedup vs baseline: 2.2836x; 2.2836x over previous
//
#include <hip/hip_runtime.h>
#include <stdint.h>

// ---------- types ----------
typedef __attribute__((ext_vector_type(8))) __bf16 bf16x8;
typedef __attribute__((ext_vector_type(4))) float floatx4;

#define DEV __device__ __forceinline__

DEV unsigned short f2bf(float f) {
    union { float f; unsigned u; } uf; uf.f = f;
    unsigned u = uf.u;
    unsigned r = (u + 0x7fffu + ((u >> 16) & 1u)) >> 16;  // RNE
    return (unsigned short)r;
}

DEV float fast_exp2(float x) {
#if __has_builtin(__builtin_amdgcn_exp2f)
    return __builtin_amdgcn_exp2f(x);
#else
    return exp2f(x);
#endif
}

DEV unsigned pack_trunc2(float lo, float hi) {
    // (trunc_bf16(hi) << 16) | trunc_bf16(lo) in one v_perm_b32
    return __builtin_amdgcn_perm(__float_as_uint(hi), __float_as_uint(lo), 0x07060302u);
}

DEV void async16(const void* g, void* l) {
    __builtin_amdgcn_global_load_lds(
        (const __attribute__((address_space(1))) void*)g,
        (__attribute__((address_space(3))) void*)l, 16, 0, 0);
}

// ---------- merged cast: x (8M f32), 4 weights (4M f32), 3 biases ----------
__global__ void cast_all_kernel(const float* __restrict__ x,
                                const float* __restrict__ Wq, const float* __restrict__ Wk,
                                const float* __restrict__ Wv, const float* __restrict__ Wo,
                                const float* __restrict__ bq, const float* __restrict__ bk,
                                const float* __restrict__ bv,
                                unsigned short* __restrict__ xb,
                                unsigned short* __restrict__ wqkv,
                                unsigned short* __restrict__ wo,
                                float* __restrict__ bqkv) {
    const int NX = 2097152;   // float4s in x
    const int NW = 262144;    // float4s per weight
    int i = blockIdx.x * blockDim.x + threadIdx.x;
    if (i < NX) {
        float4 v = reinterpret_cast<const float4*>(x)[i];
        ushort4 o;
        o.x = f2bf(v.x); o.y = f2bf(v.y); o.z = f2bf(v.z); o.w = f2bf(v.w);
        reinterpret_cast<ushort4*>(xb)[i] = o;
        return;
    }
    int j = i - NX;
    if (j < 4 * NW) {
        int seg = j >> 18, off = j & (NW - 1);
        const float* src = (seg == 0) ? Wq : (seg == 1) ? Wk : (seg == 2) ? Wv : Wo;
        unsigned short* dst = (seg < 3) ? (wqkv + seg * 1048576) : wo;
        float4 v = reinterpret_cast<const float4*>(src)[off];
        ushort4 o;
        o.x = f2bf(v.x); o.y = f2bf(v.y); o.z = f2bf(v.z); o.w = f2bf(v.w);
        reinterpret_cast<ushort4*>(dst)[off] = o;
        return;
    }
    int k = j - 4 * NW;
    if (k < 768) {  // 3 x 1024 floats of bias as float4
        int seg = k >> 8, off = k & 255;
        const float* src = (seg == 0) ? bq : (seg == 1) ? bk : bv;
        reinterpret_cast<float4*>(bqkv)[k] = reinterpret_cast<const float4*>(src)[off];
    }
}

// ---------- 128x128 GEMM, C = A(MxK) * B(NxK)^T, bf16 in, fp32 acc ----------
// Grid: x = bm, y = bn (8 consecutive blocks -> 8 XCDs share one B-tile).
// MODE 0: QKV epilogue. bn<8: Q (scaled by Dh^-0.5*log2e), 8..15: K, 16..23: V
//         V^T gets virtual-key perm v=(a&15)*4+(a>>4) per 64-key block
//         (round-0 verified pairing with the LDS-P read path in attn).
// MODE 1: out-proj epilogue (bias add, fp32 store via LDS transpose)
template <int MODE>
__global__ __launch_bounds__(256)
void gemm128(const unsigned short* __restrict__ A,   // M x K  (K-contig)
             const unsigned short* __restrict__ B,   // N x K  (K-contig)
             const float* __restrict__ bias,         // N
             unsigned short* __restrict__ q_ws,
             unsigned short* __restrict__ k_ws,
             unsigned short* __restrict__ v_ws,
             float* __restrict__ fout) {
    constexpr int K = 1024;
    __shared__ alignas(16) unsigned short smem[128 * 136];  // sA+sB / sT union
    unsigned short* sA = smem;             // 128*64
    unsigned short* sB = smem + 128 * 64;  // 128*64
    unsigned short* sT = smem;             // 128*136 (transpose staging, bf16)
    float* sT32 = reinterpret_cast<float*>(smem);  // 64*132 (fp32 staging)

    const int tid = threadIdx.x;
    const int w = tid >> 6, lane = tid & 63, quad = lane >> 4, l16 = lane & 15;
    const int wr = w >> 1, wc = w & 1;
    const int bm = blockIdx.x, bn = blockIdx.y;
    const int arow0 = bm * 128, brow0 = bn * 128;

    floatx4 acc[4][4];
#pragma unroll
    for (int i = 0; i < 4; i++)
#pragma unroll
        for (int j = 0; j < 4; j++) acc[i][j] = (floatx4){0.f, 0.f, 0.f, 0.f};

    for (int k0 = 0; k0 < K; k0 += 64) {
#pragma unroll
        for (int i = 0; i < 4; i++) {
            int cb = i * 256 + w * 64;
            int ci = cb + lane;
            int row = ci >> 3, cl = ci & 7, cs = cl ^ (row & 7);
            async16(A + (size_t)(arow0 + row) * K + k0 + cs * 8, (char*)sA + cb * 16);
            async16(B + (size_t)(brow0 + row) * K + k0 + cs * 8, (char*)sB + cb * 16);
        }
        __syncthreads();
#pragma unroll
        for (int kk = 0; kk < 2; kk++) {
            bf16x8 aF[4], bF[4];
#pragma unroll
            for (int i = 0; i < 4; i++) {
                int row = wr * 64 + i * 16 + l16;
                int c = kk * 4 + quad, ph = c ^ (row & 7);
                aF[i] = *reinterpret_cast<const bf16x8*>(sA + row * 64 + ph * 8);
            }
#pragma unroll
            for (int j = 0; j < 4; j++) {
                int row = wc * 64 + j * 16 + l16;
                int c = kk * 4 + quad, ph = c ^ (row & 7);
                bF[j] = *reinterpret_cast<const bf16x8*>(sB + row * 64 + ph * 8);
            }
#pragma unroll
            for (int i = 0; i < 4; i++)
#pragma unroll
                for (int j = 0; j < 4; j++)
                    acc[i][j] = __builtin_amdgcn_mfma_f32_16x16x32_bf16(
                        aF[i], bF[j], acc[i][j], 0, 0, 0);
        }
        __syncthreads();
    }

    if (MODE == 1) {
        // fp32 out via LDS transpose, two 64-row chunks
#pragma unroll
        for (int ch = 0; ch < 2; ch++) {
            if (ch) __syncthreads();
            if (wr == ch) {
#pragma unroll
                for (int j = 0; j < 4; j++) {
                    const int c = wc * 64 + j * 16 + l16;
                    const float bia = bias[brow0 + c];
#pragma unroll
                    for (int i = 0; i < 4; i++) {
                        int s_loc = i * 16 + quad * 4;
#pragma unroll
                        for (int r = 0; r < 4; r++)
                            sT32[(s_loc + r) * 132 + c] = acc[i][j][r] + bia;
                    }
                }
            }
            __syncthreads();
            const int cpos = (tid & 31) * 4;
#pragma unroll
            for (int it = 0; it < 8; it++) {
                int s_loc = (tid >> 5) + it * 8;
                int grow = arow0 + ch * 64 + s_loc;
                float4 vv = *reinterpret_cast<const float4*>(sT32 + s_loc * 132 + cpos);
                *reinterpret_cast<float4*>(fout + (size_t)grow * 1024 + brow0 + cpos) = vv;
            }
        }
    } else if (bn < 16) {
        // Q or K via LDS transpose -> coalesced 16B stores into (bh, s, d)
        unsigned short* dst = (bn < 8) ? q_ws : k_ws;
        const float sc = (bn < 8) ? 0.18033688f : 1.0f;  // Dh^-0.5 * log2(e) for Q
#pragma unroll
        for (int j = 0; j < 4; j++) {
            const int c = wc * 64 + j * 16 + l16;
            const float bia = bias[brow0 + c];
#pragma unroll
            for (int i = 0; i < 4; i++) {
                int s_loc = wr * 64 + i * 16 + quad * 4;
#pragma unroll
                for (int r = 0; r < 4; r++)
                    sT[(s_loc + r) * 136 + c] = f2bf((acc[i][j][r] + bia) * sc);
            }
        }
        __syncthreads();
        const int nnbase = (bn & 7) * 128;
        const int c0 = (tid & 15) * 8;
        const int h = (nnbase + c0) >> 6, d = c0 & 63;
#pragma unroll
        for (int it = 0; it < 8; it++) {
            int s_loc = (tid >> 4) + it * 16;
            int s = arow0 + s_loc;
            int bb = s >> 11, s4 = s & 2047;
            uint4 vdat = *reinterpret_cast<const uint4*>(sT + s_loc * 136 + c0);
            *reinterpret_cast<uint4*>(
                dst + ((size_t)(bb * 16 + h) * 2048 + s4) * 64 + d) = vdat;
        }
    } else {
        // V: transpose via LDS, store (bh, d, s_virtual) coalesced.
        // ROUND-0 VERIFIED 64-key virtual perm: s_local = wr*64 + a,
        // a = i*16+quad*4+r,  v = (a&15)*4 + (a>>4) = (quad*4+r)*4 + i
#pragma unroll
        for (int j = 0; j < 4; j++) {
            const int c = wc * 64 + j * 16 + l16;  // block-local col 0..127
            const float bia = bias[brow0 + c];
#pragma unroll
            for (int i = 0; i < 4; i++) {
#pragma unroll
                for (int r = 0; r < 4; r++) {
                    int v = wr * 64 + (quad * 4 + r) * 4 + i;
                    sT[c * 136 + v] = f2bf(acc[i][j][r] + bia);
                }
            }
        }
        __syncthreads();
        const int bb = bm >> 4, blk = bm & 15;
        const int chunk = tid & 15;
#pragma unroll
        for (int it = 0; it < 8; it++) {
            int row = (tid >> 4) + it * 16;   // block-local col = h*64+d part
            int h = (bn - 16) * 2 + (row >> 6), d = row & 63;
            ushort4 lo = *reinterpret_cast<const ushort4*>(sT + row * 136 + chunk * 8);
            ushort4 hi = *reinterpret_cast<const ushort4*>(sT + row * 136 + chunk * 8 + 4);
            size_t off = ((size_t)(bb * 16 + h) * 64 + d) * 2048 + blk * 128 + chunk * 8;
            *reinterpret_cast<ushort4*>(v_ws + off) = lo;
            *reinterpret_cast<ushort4*>(v_ws + off + 4) = hi;
        }
    }
}

// ---------- flash attention: one block = (bh, 128 q rows) ----------
// Round-3 verified structure (K+V LDS-staged, dbuf, one barrier/tile,
// swapped QK^T, per-wave sP round-trip) with 2x q-rows per block: each
// wave processes TWO 16-row q-groups against the SAME staged K/V tile.
// Staging bytes per MFMA halve; grid 1024 = exactly 4 blocks/CU -> one
// generation, no tail. sP reused sequentially by the two groups (same-wave
// DS ordering). LDS 40 KB. V direct-load variant (round 4) FAILED: working
// set = full 4MB L2 -> thrash (FETCH 385MB); staged-once-into-LDS is the
// correct pattern.
__global__ __launch_bounds__(256, 4)
void attn_kernel(const unsigned short* __restrict__ q_ws,
                 const unsigned short* __restrict__ k_ws,
                 const unsigned short* __restrict__ v_ws,
                 unsigned short* __restrict__ o_ws) {
    __shared__ alignas(16) unsigned short smem[20480];  // 40 KB
    // [0,4096): sK buf0   [4096,8192): sK buf1
    // [8192,12288): sVt buf0  [12288,16384): sVt buf1
    // [16384,20480): sP, wave w at +w*1024 (16 q-rows x 64 vkeys, chunk-XOR)

    const int tid = threadIdx.x;
    const int w = tid >> 6, lane = tid & 63, quad = lane >> 4, l16 = lane & 15;
    // XCD-affinity remap: all 16 q-blocks of one bh land on one XCD (id%8);
    // 8 bh per XCD. id bits: [2:0]=bh low (xcd), [6:3]=q-block, [9:7]=bh high.
    const int id = blockIdx.x;
    const int bh = (id >> 7) * 8 + (id & 7);
    const int q0 = ((id >> 3) & 15) * 128;
    const size_t base = (size_t)bh * 2048 * 64;

    unsigned short* sPw = smem + 16384 + w * 1024;

    bf16x8 aQ[2][2];
#pragma unroll
    for (int g = 0; g < 2; g++) {
        int qrow = q0 + g * 64 + w * 16 + l16;
        const unsigned short* qp = q_ws + base + (size_t)qrow * 64 + quad * 8;
        aQ[g][0] = *reinterpret_cast<const bf16x8*>(qp);
        aQ[g][1] = *reinterpret_cast<const bf16x8*>(qp + 32);
    }

    // staging: 64x64 tile = 512 chunks of 16B; 2 chunks per thread for K and V
    const unsigned short* kg[2];
    const unsigned short* vg[2];
    int loff[2];
#pragma unroll
    for (int it = 0; it < 2; it++) {
        int ci = it * 256 + tid;
        int row = ci >> 3, cl = ci & 7, cs = cl ^ (row & 7);
        kg[it] = k_ws + base + (size_t)row * 64 + cs * 8;
        vg[it] = v_ws + base + (size_t)row * 2048 + cs * 8;
        loff[it] = ci * 8;  // shorts
    }

    const __bf16 one = (__bf16)1.0f;
    const bf16x8 vOnes = {one, one, one, one, one, one, one, one};

    floatx4 oAcc[2][4], rsAcc[2];
#pragma unroll
    for (int g = 0; g < 2; g++) {
#pragma unroll
        for (int j = 0; j < 4; j++) oAcc[g][j] = (floatx4){0.f, 0.f, 0.f, 0.f};
        rsAcc[g] = (floatx4){0.f, 0.f, 0.f, 0.f};
    }

    // prologue: stage tile 0 into buf 0
    {
#pragma unroll
        for (int it = 0; it < 2; it++) {
            async16(kg[it], smem + loff[it]);
            async16(vg[it], smem + 8192 + loff[it]);
        }
    }

    for (int t = 0; t < 32; t++) {
        const int b = t & 1;
        const unsigned short* sK = smem + b * 4096;
        const unsigned short* sVt = smem + 8192 + b * 4096;
        __syncthreads();  // tile t staged (vmcnt drain); buf b^1 free for reuse

        if (t < 31) {
            const int kv0 = (t + 1) * 64;
            unsigned short* dK = smem + (b ^ 1) * 4096;
            unsigned short* dV = smem + 8192 + (b ^ 1) * 4096;
#pragma unroll
            for (int it = 0; it < 2; it++) {
                async16(kg[it] + (size_t)kv0 * 64, dK + loff[it]);
                async16(vg[it] + kv0, dV + loff[it]);
            }
        }

#pragma unroll
        for (int g = 0; g < 2; g++) {
            // S'^T = K Q'^T over 64 keys (log2e, 1/sqrt(Dh) pre-folded in Q).
            // sAcc[j][r] at lane (quad,l16): key = 16j + 4quad + r, q = l16.
            floatx4 sAcc[4];
#pragma unroll
            for (int j = 0; j < 4; j++) sAcc[j] = (floatx4){0.f, 0.f, 0.f, 0.f};
#pragma unroll
            for (int kk = 0; kk < 2; kk++) {
#pragma unroll
                for (int j = 0; j < 4; j++) {
                    int krow = j * 16 + l16;
                    int ph = (kk * 4 + quad) ^ (krow & 7);
                    bf16x8 aK = *reinterpret_cast<const bf16x8*>(sK + krow * 64 + ph * 8);
                    sAcc[j] = __builtin_amdgcn_mfma_f32_16x16x32_bf16(
                        aK, aQ[g][kk], sAcc[j], 0, 0, 0);
                }
            }

            // p = exp2(s'^T); lane owns q-row l16, writes positions
            // p = 16*quad + 4*r + j (two 16B chunks, chunk-XOR layout)
            {
                float e00 = fast_exp2(sAcc[0][0]), e10 = fast_exp2(sAcc[1][0]);
                float e20 = fast_exp2(sAcc[2][0]), e30 = fast_exp2(sAcc[3][0]);
                float e01 = fast_exp2(sAcc[0][1]), e11 = fast_exp2(sAcc[1][1]);
                float e21 = fast_exp2(sAcc[2][1]), e31 = fast_exp2(sAcc[3][1]);
                float e02 = fast_exp2(sAcc[0][2]), e12 = fast_exp2(sAcc[1][2]);
                float e22 = fast_exp2(sAcc[2][2]), e32 = fast_exp2(sAcc[3][2]);
                float e03 = fast_exp2(sAcc[0][3]), e13 = fast_exp2(sAcc[1][3]);
                float e23 = fast_exp2(sAcc[2][3]), e33 = fast_exp2(sAcc[3][3]);
                uint4 w0, w1;
                w0.x = pack_trunc2(e00, e10);
                w0.y = pack_trunc2(e20, e30);
                w0.z = pack_trunc2(e01, e11);
                w0.w = pack_trunc2(e21, e31);
                w1.x = pack_trunc2(e02, e12);
                w1.y = pack_trunc2(e22, e32);
                w1.z = pack_trunc2(e03, e13);
                w1.w = pack_trunc2(e23, e33);
                const int xr = l16 & 7;
                *reinterpret_cast<uint4*>(sPw + l16 * 64 + (((2 * quad) ^ xr) << 3)) = w0;
                *reinterpret_cast<uint4*>(sPw + l16 * 64 + (((2 * quad + 1) ^ xr) << 3)) = w1;
            }
            asm volatile("s_waitcnt lgkmcnt(0)" ::: "memory");
            __builtin_amdgcn_sched_barrier(0);

            // O += P V ; rowsum += P * ones  (round-0 verified read path)
            bf16x8 aP[2];
#pragma unroll
            for (int ks = 0; ks < 2; ks++)
                aP[ks] = *reinterpret_cast<const bf16x8*>(
                    sPw + l16 * 64 + (((ks * 4 + quad) ^ (l16 & 7)) << 3));
#pragma unroll
            for (int jd = 0; jd < 4; jd++) {
                int drow = jd * 16 + l16;
#pragma unroll
                for (int ks = 0; ks < 2; ks++) {
                    int ph = (ks * 4 + quad) ^ (drow & 7);
                    bf16x8 bV = *reinterpret_cast<const bf16x8*>(sVt + drow * 64 + ph * 8);
                    oAcc[g][jd] = __builtin_amdgcn_mfma_f32_16x16x32_bf16(
                        aP[ks], bV, oAcc[g][jd], 0, 0, 0);
                }
            }
#pragma unroll
            for (int ks = 0; ks < 2; ks++)
                rsAcc[g] = __builtin_amdgcn_mfma_f32_16x16x32_bf16(
                    aP[ks], vOnes, rsAcc[g], 0, 0, 0);
        }
    }

    // epilogue: rsAcc[g][r] = row sum for q=g*64+w*16+quad*4+r (repl. l16)
    const int bb = bh >> 4, h = bh & 15;
#pragma unroll
    for (int g = 0; g < 2; g++) {
        float inv[4];
#pragma unroll
        for (int r = 0; r < 4; r++) inv[r] = 1.0f / rsAcc[g][r];
#pragma unroll
        for (int jd = 0; jd < 4; jd++) {
            int d = jd * 16 + l16;
#pragma unroll
            for (int r = 0; r < 4; r++) {
                int s = q0 + g * 64 + w * 16 + quad * 4 + r;
                float v = oAcc[g][jd][r] * inv[r];
                o_ws[((size_t)bb * 2048 + s) * 1024 + h * 64 + d] = f2bf(v);
            }
        }
    }
}

// ---------- launch ----------
extern "C" void kernel_launch(void* const* d_in, const int* in_sizes, int n_in,
                              void* d_out, int out_size, void* d_ws, size_t ws_size,
                              hipStream_t stream) {
    const float* x  = (const float*)d_in[0];
    const float* Wq = (const float*)d_in[1];
    const float* bq = (const float*)d_in[2];
    const float* Wk = (const float*)d_in[3];
    const float* bk = (const float*)d_in[4];
    const float* Wv = (const float*)d_in[5];
    const float* bv = (const float*)d_in[6];
    const float* Wo = (const float*)d_in[7];
    const float* bo = (const float*)d_in[8];
    float* out = (float*)d_out;

    char* ws = (char*)d_ws;
    unsigned short* xb   = (unsigned short*)(ws);                       // 16 MB
    unsigned short* wqkv = (unsigned short*)(ws + (16ull << 20));       // 6 MB
    unsigned short* wo   = (unsigned short*)(ws + (22ull << 20));       // 2 MB
    float*          bqkv = (float*)(ws + (24ull << 20));                // 12 KB
    unsigned short* q_ws = (unsigned short*)(ws + (25ull << 20));       // 16 MB
    unsigned short* k_ws = (unsigned short*)(ws + (41ull << 20));       // 16 MB
    unsigned short* v_ws = (unsigned short*)(ws + (57ull << 20));       // 16 MB
    unsigned short* o_ws = xb;  // alias: x_bf dead after QKV GEMM

    // one cast kernel: 2097152 (x) + 1048576 (W) + 768 (bias) float4 slots
    cast_all_kernel<<<12291, 256, 0, stream>>>(x, Wq, Wk, Wv, Wo, bq, bk, bv,
                                               xb, wqkv, wo, bqkv);

    gemm128<0><<<dim3(64, 24), 256, 0, stream>>>(xb, wqkv, bqkv, q_ws, k_ws, v_ws, nullptr);
    attn_kernel<<<1024, 256, 0, stream>>>(q_ws, k_ws, v_ws, o_ws);
    gemm128<1><<<dim3(64, 8), 256, 0, stream>>>(o_ws, wo, bo, nullptr, nullptr, nullptr, out);
}

// Round 6
// 266.535 us; speedup vs baseline: 2.3637x; 1.0351x over previous
//
#include <hip/hip_runtime.h>
#include <stdint.h>

// ---------- types ----------
typedef __attribute__((ext_vector_type(8))) __bf16 bf16x8;
typedef __attribute__((ext_vector_type(4))) float floatx4;

#define DEV __device__ __forceinline__

DEV unsigned short f2bf(float f) {
    union { float f; unsigned u; } uf; uf.f = f;
    unsigned u = uf.u;
    unsigned r = (u + 0x7fffu + ((u >> 16) & 1u)) >> 16;  // RNE
    return (unsigned short)r;
}

DEV float fast_exp2(float x) {
#if __has_builtin(__builtin_amdgcn_exp2f)
    return __builtin_amdgcn_exp2f(x);
#else
    return exp2f(x);
#endif
}

DEV unsigned pack_trunc2(float lo, float hi) {
    // (trunc_bf16(hi) << 16) | trunc_bf16(lo) in one v_perm_b32
    return __builtin_amdgcn_perm(__float_as_uint(hi), __float_as_uint(lo), 0x07060302u);
}

DEV void async16(const void* g, void* l) {
    __builtin_amdgcn_global_load_lds(
        (const __attribute__((address_space(1))) void*)g,
        (__attribute__((address_space(3))) void*)l, 16, 0, 0);
}

// ---------- merged cast: x (8M f32), 4 weights (4M f32), 3 biases ----------
__global__ void cast_all_kernel(const float* __restrict__ x,
                                const float* __restrict__ Wq, const float* __restrict__ Wk,
                                const float* __restrict__ Wv, const float* __restrict__ Wo,
                                const float* __restrict__ bq, const float* __restrict__ bk,
                                const float* __restrict__ bv,
                                unsigned short* __restrict__ xb,
                                unsigned short* __restrict__ wqkv,
                                unsigned short* __restrict__ wo,
                                float* __restrict__ bqkv) {
    const int NX = 2097152;   // float4s in x
    const int NW = 262144;    // float4s per weight
    int i = blockIdx.x * blockDim.x + threadIdx.x;
    if (i < NX) {
        float4 v = reinterpret_cast<const float4*>(x)[i];
        ushort4 o;
        o.x = f2bf(v.x); o.y = f2bf(v.y); o.z = f2bf(v.z); o.w = f2bf(v.w);
        reinterpret_cast<ushort4*>(xb)[i] = o;
        return;
    }
    int j = i - NX;
    if (j < 4 * NW) {
        int seg = j >> 18, off = j & (NW - 1);
        const float* src = (seg == 0) ? Wq : (seg == 1) ? Wk : (seg == 2) ? Wv : Wo;
        unsigned short* dst = (seg < 3) ? (wqkv + seg * 1048576) : wo;
        float4 v = reinterpret_cast<const float4*>(src)[off];
        ushort4 o;
        o.x = f2bf(v.x); o.y = f2bf(v.y); o.z = f2bf(v.z); o.w = f2bf(v.w);
        reinterpret_cast<ushort4*>(dst)[off] = o;
        return;
    }
    int k = j - 4 * NW;
    if (k < 768) {  // 3 x 1024 floats of bias as float4
        int seg = k >> 8, off = k & 255;
        const float* src = (seg == 0) ? bq : (seg == 1) ? bk : bv;
        reinterpret_cast<float4*>(bqkv)[k] = reinterpret_cast<const float4*>(src)[off];
    }
}

// ---------- 128x128 GEMM, C = A(MxK) * B(NxK)^T, bf16 in, fp32 acc ----------
// Grid: x = bm, y = bn (8 consecutive blocks -> 8 XCDs share one B-tile).
// MODE 0: QKV epilogue. bn<8: Q (scaled by Dh^-0.5*log2e), 8..15: K, 16..23: V
//         V^T gets virtual-key perm v=(a&15)*4+(a>>4) per 64-key block
//         (round-0 verified pairing with the LDS-P read path in attn).
template <int MODE>
__global__ __launch_bounds__(256)
void gemm128(const unsigned short* __restrict__ A,   // M x K  (K-contig)
             const unsigned short* __restrict__ B,   // N x K  (K-contig)
             const float* __restrict__ bias,         // N
             unsigned short* __restrict__ q_ws,
             unsigned short* __restrict__ k_ws,
             unsigned short* __restrict__ v_ws,
             float* __restrict__ fout) {
    constexpr int K = 1024;
    __shared__ alignas(16) unsigned short smem[128 * 136];  // sA+sB / sT union
    unsigned short* sA = smem;             // 128*64
    unsigned short* sB = smem + 128 * 64;  // 128*64
    unsigned short* sT = smem;             // 128*136 (transpose staging, bf16)

    const int tid = threadIdx.x;
    const int w = tid >> 6, lane = tid & 63, quad = lane >> 4, l16 = lane & 15;
    const int wr = w >> 1, wc = w & 1;
    const int bm = blockIdx.x, bn = blockIdx.y;
    const int arow0 = bm * 128, brow0 = bn * 128;

    floatx4 acc[4][4];
#pragma unroll
    for (int i = 0; i < 4; i++)
#pragma unroll
        for (int j = 0; j < 4; j++) acc[i][j] = (floatx4){0.f, 0.f, 0.f, 0.f};

    for (int k0 = 0; k0 < K; k0 += 64) {
#pragma unroll
        for (int i = 0; i < 4; i++) {
            int cb = i * 256 + w * 64;
            int ci = cb + lane;
            int row = ci >> 3, cl = ci & 7, cs = cl ^ (row & 7);
            async16(A + (size_t)(arow0 + row) * K + k0 + cs * 8, (char*)sA + cb * 16);
            async16(B + (size_t)(brow0 + row) * K + k0 + cs * 8, (char*)sB + cb * 16);
        }
        __syncthreads();
#pragma unroll
        for (int kk = 0; kk < 2; kk++) {
            bf16x8 aF[4], bF[4];
#pragma unroll
            for (int i = 0; i < 4; i++) {
                int row = wr * 64 + i * 16 + l16;
                int c = kk * 4 + quad, ph = c ^ (row & 7);
                aF[i] = *reinterpret_cast<const bf16x8*>(sA + row * 64 + ph * 8);
            }
#pragma unroll
            for (int j = 0; j < 4; j++) {
                int row = wc * 64 + j * 16 + l16;
                int c = kk * 4 + quad, ph = c ^ (row & 7);
                bF[j] = *reinterpret_cast<const bf16x8*>(sB + row * 64 + ph * 8);
            }
#pragma unroll
            for (int i = 0; i < 4; i++)
#pragma unroll
                for (int j = 0; j < 4; j++)
                    acc[i][j] = __builtin_amdgcn_mfma_f32_16x16x32_bf16(
                        aF[i], bF[j], acc[i][j], 0, 0, 0);
        }
        __syncthreads();
    }

    if (bn < 16) {
        // Q or K via LDS transpose -> coalesced 16B stores into (bh, s, d)
        unsigned short* dst = (bn < 8) ? q_ws : k_ws;
        const float sc = (bn < 8) ? 0.18033688f : 1.0f;  // Dh^-0.5 * log2(e) for Q
#pragma unroll
        for (int j = 0; j < 4; j++) {
            const int c = wc * 64 + j * 16 + l16;
            const float bia = bias[brow0 + c];
#pragma unroll
            for (int i = 0; i < 4; i++) {
                int s_loc = wr * 64 + i * 16 + quad * 4;
#pragma unroll
                for (int r = 0; r < 4; r++)
                    sT[(s_loc + r) * 136 + c] = f2bf((acc[i][j][r] + bia) * sc);
            }
        }
        __syncthreads();
        const int nnbase = (bn & 7) * 128;
        const int c0 = (tid & 15) * 8;
        const int h = (nnbase + c0) >> 6, d = c0 & 63;
#pragma unroll
        for (int it = 0; it < 8; it++) {
            int s_loc = (tid >> 4) + it * 16;
            int s = arow0 + s_loc;
            int bb = s >> 11, s4 = s & 2047;
            uint4 vdat = *reinterpret_cast<const uint4*>(sT + s_loc * 136 + c0);
            *reinterpret_cast<uint4*>(
                dst + ((size_t)(bb * 16 + h) * 2048 + s4) * 64 + d) = vdat;
        }
    } else {
        // V: transpose via LDS, store (bh, d, s_virtual) coalesced.
        // ROUND-0 VERIFIED 64-key virtual perm: s_local = wr*64 + a,
        // a = i*16+quad*4+r,  v = (a&15)*4 + (a>>4) = (quad*4+r)*4 + i
#pragma unroll
        for (int j = 0; j < 4; j++) {
            const int c = wc * 64 + j * 16 + l16;  // block-local col 0..127
            const float bia = bias[brow0 + c];
#pragma unroll
            for (int i = 0; i < 4; i++) {
#pragma unroll
                for (int r = 0; r < 4; r++) {
                    int v = wr * 64 + (quad * 4 + r) * 4 + i;
                    sT[c * 136 + v] = f2bf(acc[i][j][r] + bia);
                }
            }
        }
        __syncthreads();
        const int bb = bm >> 4, blk = bm & 15;
        const int chunk = tid & 15;
#pragma unroll
        for (int it = 0; it < 8; it++) {
            int row = (tid >> 4) + it * 16;   // block-local col = h*64+d part
            int h = (bn - 16) * 2 + (row >> 6), d = row & 63;
            ushort4 lo = *reinterpret_cast<const ushort4*>(sT + row * 136 + chunk * 8);
            ushort4 hi = *reinterpret_cast<const ushort4*>(sT + row * 136 + chunk * 8 + 4);
            size_t off = ((size_t)(bb * 16 + h) * 64 + d) * 2048 + blk * 128 + chunk * 8;
            *reinterpret_cast<ushort4*>(v_ws + off) = lo;
            *reinterpret_cast<ushort4*>(v_ws + off + 4) = hi;
        }
    }
}

// ---------- out-proj GEMM: 128x64 tile, grid (64,16) = 1024 blocks ----------
// M=8192, N=1024, K=1024. 4 blocks/CU fully resident (vs 2 with 128x128),
// 16 waves/CU. Same staging swizzle / fragment paths as gemm128.
__global__ __launch_bounds__(256)
void gemm_oproj(const unsigned short* __restrict__ A,   // 8192 x 1024
                const unsigned short* __restrict__ Bw,  // 1024 x 1024
                const float* __restrict__ bias,         // 1024
                float* __restrict__ fout) {
    constexpr int K = 1024;
    __shared__ alignas(16) unsigned short smem[192 * 64];  // 24 KB
    unsigned short* sA = smem;             // 128*64
    unsigned short* sB = smem + 128 * 64;  // 64*64
    float* sT32 = reinterpret_cast<float*>(smem);  // 64*68 f32 = 17408 B

    const int tid = threadIdx.x;
    const int w = tid >> 6, lane = tid & 63, quad = lane >> 4, l16 = lane & 15;
    const int wr = w >> 1, wc = w & 1;
    const int bm = blockIdx.x, bn = blockIdx.y;
    const int arow0 = bm * 128, brow0 = bn * 64;

    floatx4 acc[4][2];
#pragma unroll
    for (int i = 0; i < 4; i++)
#pragma unroll
        for (int j = 0; j < 2; j++) acc[i][j] = (floatx4){0.f, 0.f, 0.f, 0.f};

    for (int k0 = 0; k0 < K; k0 += 64) {
#pragma unroll
        for (int i = 0; i < 4; i++) {  // A: 1024 chunks, 4/thread
            int ci = i * 256 + tid;
            int row = ci >> 3, cs = (ci & 7) ^ (row & 7);
            async16(A + (size_t)(arow0 + row) * K + k0 + cs * 8, (char*)sA + ci * 16);
        }
#pragma unroll
        for (int i = 0; i < 2; i++) {  // B: 512 chunks, 2/thread
            int ci = i * 256 + tid;
            int row = ci >> 3, cs = (ci & 7) ^ (row & 7);
            async16(Bw + (size_t)(brow0 + row) * K + k0 + cs * 8, (char*)sB + ci * 16);
        }
        __syncthreads();
#pragma unroll
        for (int kk = 0; kk < 2; kk++) {
            bf16x8 aF[4], bF[2];
#pragma unroll
            for (int i = 0; i < 4; i++) {
                int row = wr * 64 + i * 16 + l16;
                int ph = (kk * 4 + quad) ^ (row & 7);
                aF[i] = *reinterpret_cast<const bf16x8*>(sA + row * 64 + ph * 8);
            }
#pragma unroll
            for (int j = 0; j < 2; j++) {
                int row = wc * 32 + j * 16 + l16;
                int ph = (kk * 4 + quad) ^ (row & 7);
                bF[j] = *reinterpret_cast<const bf16x8*>(sB + row * 64 + ph * 8);
            }
#pragma unroll
            for (int i = 0; i < 4; i++)
#pragma unroll
                for (int j = 0; j < 2; j++)
                    acc[i][j] = __builtin_amdgcn_mfma_f32_16x16x32_bf16(
                        aF[i], bF[j], acc[i][j], 0, 0, 0);
        }
        __syncthreads();
    }

    // epilogue: fp32 out via LDS transpose, two 64-row chunks
#pragma unroll
    for (int ch = 0; ch < 2; ch++) {
        if (ch) __syncthreads();
        if (wr == ch) {
#pragma unroll
            for (int j = 0; j < 2; j++) {
                const int c = wc * 32 + j * 16 + l16;
                const float bia = bias[brow0 + c];
#pragma unroll
                for (int i = 0; i < 4; i++) {
                    int s_loc = i * 16 + quad * 4;
#pragma unroll
                    for (int r = 0; r < 4; r++)
                        sT32[(s_loc + r) * 68 + c] = acc[i][j][r] + bia;
                }
            }
        }
        __syncthreads();
        const int cpos = (tid & 15) * 4;
#pragma unroll
        for (int it = 0; it < 4; it++) {
            int s_loc = (tid >> 4) + it * 16;
            int grow = arow0 + ch * 64 + s_loc;
            float4 vv = *reinterpret_cast<const float4*>(sT32 + s_loc * 68 + cpos);
            *reinterpret_cast<float4*>(fout + (size_t)grow * 1024 + brow0 + cpos) = vv;
        }
    }
}

// ---------- flash attention: one block = (bh, 128 q rows) ----------
// Round-5 structure with the serial chain re-pipelined:
//  - shared aK loads feed BOTH q-groups' QK MFMAs (8 ds_reads/tile, was 16)
//  - group-1 exp pass covers group-0's sP write latency
//  - group-1 sP write issued after group-0's aP reads (same-wave DS FIFO +
//    C++ may-alias ordering keeps read-before-write), covered by PV0 MFMAs
// LDS 40 KB, 4 blocks/CU.
__global__ __launch_bounds__(256, 4)
void attn_kernel(const unsigned short* __restrict__ q_ws,
                 const unsigned short* __restrict__ k_ws,
                 const unsigned short* __restrict__ v_ws,
                 unsigned short* __restrict__ o_ws) {
    __shared__ alignas(16) unsigned short smem[20480];  // 40 KB
    // [0,4096): sK buf0   [4096,8192): sK buf1
    // [8192,12288): sVt buf0  [12288,16384): sVt buf1
    // [16384,20480): sP, wave w at +w*1024 (16 q-rows x 64 vkeys, chunk-XOR)

    const int tid = threadIdx.x;
    const int w = tid >> 6, lane = tid & 63, quad = lane >> 4, l16 = lane & 15;
    // XCD-affinity remap: all 16 q-blocks of one bh land on one XCD (id%8)
    const int id = blockIdx.x;
    const int bh = (id >> 7) * 8 + (id & 7);
    const int q0 = ((id >> 3) & 15) * 128;
    const size_t base = (size_t)bh * 2048 * 64;

    unsigned short* sPw = smem + 16384 + w * 1024;

    bf16x8 aQ[2][2];
#pragma unroll
    for (int g = 0; g < 2; g++) {
        int qrow = q0 + g * 64 + w * 16 + l16;
        const unsigned short* qp = q_ws + base + (size_t)qrow * 64 + quad * 8;
        aQ[g][0] = *reinterpret_cast<const bf16x8*>(qp);
        aQ[g][1] = *reinterpret_cast<const bf16x8*>(qp + 32);
    }

    // staging: 64x64 tile = 512 chunks of 16B; 2 chunks per thread for K and V
    const unsigned short* kg[2];
    const unsigned short* vg[2];
    int loff[2];
#pragma unroll
    for (int it = 0; it < 2; it++) {
        int ci = it * 256 + tid;
        int row = ci >> 3, cl = ci & 7, cs = cl ^ (row & 7);
        kg[it] = k_ws + base + (size_t)row * 64 + cs * 8;
        vg[it] = v_ws + base + (size_t)row * 2048 + cs * 8;
        loff[it] = ci * 8;  // shorts
    }

    const __bf16 one = (__bf16)1.0f;
    const bf16x8 vOnes = {one, one, one, one, one, one, one, one};

    floatx4 oAcc[2][4], rsAcc[2];
#pragma unroll
    for (int g = 0; g < 2; g++) {
#pragma unroll
        for (int j = 0; j < 4; j++) oAcc[g][j] = (floatx4){0.f, 0.f, 0.f, 0.f};
        rsAcc[g] = (floatx4){0.f, 0.f, 0.f, 0.f};
    }

    // prologue: stage tile 0 into buf 0
    {
#pragma unroll
        for (int it = 0; it < 2; it++) {
            async16(kg[it], smem + loff[it]);
            async16(vg[it], smem + 8192 + loff[it]);
        }
    }

    const int xr = l16 & 7;
    const int offw0 = l16 * 64 + (((2 * quad) ^ xr) << 3);
    const int offw1 = l16 * 64 + (((2 * quad + 1) ^ xr) << 3);
    const int offr0 = l16 * 64 + ((quad ^ xr) << 3);
    const int offr1 = l16 * 64 + (((4 + quad) ^ xr) << 3);

    for (int t = 0; t < 32; t++) {
        const int b = t & 1;
        const unsigned short* sK = smem + b * 4096;
        const unsigned short* sVt = smem + 8192 + b * 4096;
        __syncthreads();  // tile t staged (vmcnt drain); buf b^1 free for reuse

        if (t < 31) {
            const int kv0 = (t + 1) * 64;
            unsigned short* dK = smem + (b ^ 1) * 4096;
            unsigned short* dV = smem + 8192 + (b ^ 1) * 4096;
#pragma unroll
            for (int it = 0; it < 2; it++) {
                async16(kg[it] + (size_t)kv0 * 64, dK + loff[it]);
                async16(vg[it] + kv0, dV + loff[it]);
            }
        }

        // S'^T = K Q'^T for BOTH groups, sharing each aK load.
        // s{0,1}[j][r] at lane (quad,l16): key = 16j + 4quad + r, q = l16.
        floatx4 s0[4], s1[4];
#pragma unroll
        for (int j = 0; j < 4; j++) {
            s0[j] = (floatx4){0.f, 0.f, 0.f, 0.f};
            s1[j] = (floatx4){0.f, 0.f, 0.f, 0.f};
        }
#pragma unroll
        for (int kk = 0; kk < 2; kk++) {
#pragma unroll
            for (int j = 0; j < 4; j++) {
                int krow = j * 16 + l16;
                int ph = (kk * 4 + quad) ^ (krow & 7);
                bf16x8 aK = *reinterpret_cast<const bf16x8*>(sK + krow * 64 + ph * 8);
                s0[j] = __builtin_amdgcn_mfma_f32_16x16x32_bf16(aK, aQ[0][kk], s0[j], 0, 0, 0);
                s1[j] = __builtin_amdgcn_mfma_f32_16x16x32_bf16(aK, aQ[1][kk], s1[j], 0, 0, 0);
            }
        }

        // group 0: exp in place, pack, write sP
#pragma unroll
        for (int j = 0; j < 4; j++)
#pragma unroll
            for (int r = 0; r < 4; r++) s0[j][r] = fast_exp2(s0[j][r]);
        {
            uint4 w0, w1;
            w0.x = pack_trunc2(s0[0][0], s0[1][0]);
            w0.y = pack_trunc2(s0[2][0], s0[3][0]);
            w0.z = pack_trunc2(s0[0][1], s0[1][1]);
            w0.w = pack_trunc2(s0[2][1], s0[3][1]);
            w1.x = pack_trunc2(s0[0][2], s0[1][2]);
            w1.y = pack_trunc2(s0[2][2], s0[3][2]);
            w1.z = pack_trunc2(s0[0][3], s0[1][3]);
            w1.w = pack_trunc2(s0[2][3], s0[3][3]);
            *reinterpret_cast<uint4*>(sPw + offw0) = w0;
            *reinterpret_cast<uint4*>(sPw + offw1) = w1;
        }

        // group 1 exp pass covers the sP0 write latency
#pragma unroll
        for (int j = 0; j < 4; j++)
#pragma unroll
            for (int r = 0; r < 4; r++) s1[j][r] = fast_exp2(s1[j][r]);

        asm volatile("s_waitcnt lgkmcnt(0)" ::: "memory");
        __builtin_amdgcn_sched_barrier(0);

        // group 0: read aP, PV, rowsum
        {
            bf16x8 aPa = *reinterpret_cast<const bf16x8*>(sPw + offr0);
            bf16x8 aPb = *reinterpret_cast<const bf16x8*>(sPw + offr1);
#pragma unroll
            for (int jd = 0; jd < 4; jd++) {
                int drow = jd * 16 + l16;
                int ph0 = quad ^ (drow & 7);
                bf16x8 bVa = *reinterpret_cast<const bf16x8*>(sVt + drow * 64 + ph0 * 8);
                oAcc[0][jd] = __builtin_amdgcn_mfma_f32_16x16x32_bf16(aPa, bVa, oAcc[0][jd], 0, 0, 0);
                int ph1 = (4 + quad) ^ (drow & 7);
                bf16x8 bVb = *reinterpret_cast<const bf16x8*>(sVt + drow * 64 + ph1 * 8);
                oAcc[0][jd] = __builtin_amdgcn_mfma_f32_16x16x32_bf16(aPb, bVb, oAcc[0][jd], 0, 0, 0);
            }
            rsAcc[0] = __builtin_amdgcn_mfma_f32_16x16x32_bf16(aPa, vOnes, rsAcc[0], 0, 0, 0);
            rsAcc[0] = __builtin_amdgcn_mfma_f32_16x16x32_bf16(aPb, vOnes, rsAcc[0], 0, 0, 0);
        }

        // group 1: pack, write sP (after group-0 aP reads: same-wave DS FIFO
        // + C++ may-alias ordering keep read-before-write); PV0 covers it
        {
            uint4 w0, w1;
            w0.x = pack_trunc2(s1[0][0], s1[1][0]);
            w0.y = pack_trunc2(s1[2][0], s1[3][0]);
            w0.z = pack_trunc2(s1[0][1], s1[1][1]);
            w0.w = pack_trunc2(s1[2][1], s1[3][1]);
            w1.x = pack_trunc2(s1[0][2], s1[1][2]);
            w1.y = pack_trunc2(s1[2][2], s1[3][2]);
            w1.z = pack_trunc2(s1[0][3], s1[1][3]);
            w1.w = pack_trunc2(s1[2][3], s1[3][3]);
            *reinterpret_cast<uint4*>(sPw + offw0) = w0;
            *reinterpret_cast<uint4*>(sPw + offw1) = w1;
        }

        asm volatile("s_waitcnt lgkmcnt(0)" ::: "memory");
        __builtin_amdgcn_sched_barrier(0);

        // group 1: read aP, PV, rowsum
        {
            bf16x8 aPa = *reinterpret_cast<const bf16x8*>(sPw + offr0);
            bf16x8 aPb = *reinterpret_cast<const bf16x8*>(sPw + offr1);
#pragma unroll
            for (int jd = 0; jd < 4; jd++) {
                int drow = jd * 16 + l16;
                int ph0 = quad ^ (drow & 7);
                bf16x8 bVa = *reinterpret_cast<const bf16x8*>(sVt + drow * 64 + ph0 * 8);
                oAcc[1][jd] = __builtin_amdgcn_mfma_f32_16x16x32_bf16(aPa, bVa, oAcc[1][jd], 0, 0, 0);
                int ph1 = (4 + quad) ^ (drow & 7);
                bf16x8 bVb = *reinterpret_cast<const bf16x8*>(sVt + drow * 64 + ph1 * 8);
                oAcc[1][jd] = __builtin_amdgcn_mfma_f32_16x16x32_bf16(aPb, bVb, oAcc[1][jd], 0, 0, 0);
            }
            rsAcc[1] = __builtin_amdgcn_mfma_f32_16x16x32_bf16(aPa, vOnes, rsAcc[1], 0, 0, 0);
            rsAcc[1] = __builtin_amdgcn_mfma_f32_16x16x32_bf16(aPb, vOnes, rsAcc[1], 0, 0, 0);
        }
    }

    // epilogue: rsAcc[g][r] = row sum for q=g*64+w*16+quad*4+r (repl. l16)
    const int bb = bh >> 4, h = bh & 15;
#pragma unroll
    for (int g = 0; g < 2; g++) {
        float inv[4];
#pragma unroll
        for (int r = 0; r < 4; r++) inv[r] = 1.0f / rsAcc[g][r];
#pragma unroll
        for (int jd = 0; jd < 4; jd++) {
            int d = jd * 16 + l16;
#pragma unroll
            for (int r = 0; r < 4; r++) {
                int s = q0 + g * 64 + w * 16 + quad * 4 + r;
                float v = oAcc[g][jd][r] * inv[r];
                o_ws[((size_t)bb * 2048 + s) * 1024 + h * 64 + d] = f2bf(v);
            }
        }
    }
}

// ---------- launch ----------
extern "C" void kernel_launch(void* const* d_in, const int* in_sizes, int n_in,
                              void* d_out, int out_size, void* d_ws, size_t ws_size,
                              hipStream_t stream) {
    const float* x  = (const float*)d_in[0];
    const float* Wq = (const float*)d_in[1];
    const float* bq = (const float*)d_in[2];
    const float* Wk = (const float*)d_in[3];
    const float* bk = (const float*)d_in[4];
    const float* Wv = (const float*)d_in[5];
    const float* bv = (const float*)d_in[6];
    const float* Wo = (const float*)d_in[7];
    const float* bo = (const float*)d_in[8];
    float* out = (float*)d_out;

    char* ws = (char*)d_ws;
    unsigned short* xb   = (unsigned short*)(ws);                       // 16 MB
    unsigned short* wqkv = (unsigned short*)(ws + (16ull << 20));       // 6 MB
    unsigned short* wo   = (unsigned short*)(ws + (22ull << 20));       // 2 MB
    float*          bqkv = (float*)(ws + (24ull << 20));                // 12 KB
    unsigned short* q_ws = (unsigned short*)(ws + (25ull << 20));       // 16 MB
    unsigned short* k_ws = (unsigned short*)(ws + (41ull << 20));       // 16 MB
    unsigned short* v_ws = (unsigned short*)(ws + (57ull << 20));       // 16 MB
    unsigned short* o_ws = xb;  // alias: x_bf dead after QKV GEMM

    // one cast kernel: 2097152 (x) + 1048576 (W) + 768 (bias) float4 slots
    cast_all_kernel<<<12291, 256, 0, stream>>>(x, Wq, Wk, Wv, Wo, bq, bk, bv,
                                               xb, wqkv, wo, bqkv);

    gemm128<0><<<dim3(64, 24), 256, 0, stream>>>(xb, wqkv, bqkv, q_ws, k_ws, v_ws, nullptr);
    attn_kernel<<<1024, 256, 0, stream>>>(q_ws, k_ws, v_ws, o_ws);
    gemm_oproj<<<dim3(64, 16), 256, 0, stream>>>(o_ws, wo, bo, out);
}